// Round 5
// baseline (2058.593 us; speedup 1.0000x reference)
//
#include <hip/hip_runtime.h>

// WL2 graph-conv layer, MI355X — round 5: bucket-binned edges + LDS-atomic gather.
// transpose_w -> memset(cursor) -> fill_bucket (bin edges by row>>7, fixed cap)
//   -> neighbor_mfma (XWnh = f16(X@Wn + bn/2), emits Xh)
//   -> gather_lds (per 128-row bucket: conv tile in LDS via ds_add_f32, flush f16)
//   -> final_mfma (out = relu(Xh@Wl + (Xh@Wf)*conv + b))
// ws: [XWnh 51.2MB][Xh 51.2MB][convh 51.2MB][WlT/WfT/WnT 96KB][cursor][binned 22.4MB] ~176MB

constexpr int DIM = 128;
constexpr int BROWS = 128;   // rows per bucket
constexpr int BCAP = 1792;   // capacity: mean 1280, sigma ~36 -> 14 sigma headroom

typedef _Float16 half_t;
typedef __attribute__((ext_vector_type(8))) _Float16 half8;
typedef __attribute__((ext_vector_type(2))) _Float16 half2v;
typedef __attribute__((ext_vector_type(4))) float f32x4;

// ---------------- edge binning ----------------
__global__ __launch_bounds__(256) void fill_bucket_k(
    const int* __restrict__ ra, const int* __restrict__ rb,
    const int* __restrict__ br, int* __restrict__ cursor,
    int2* __restrict__ binned, int E) {
  const int e = blockIdx.x * 256 + threadIdx.x;
  if (e >= E) return;
  const int row = br[e];
  const int bucket = row >> 7;
  const int lrow = row & 127;
  const int pos = atomicAdd(&cursor[bucket], 1);
  if (pos < BCAP)
    binned[(long)bucket * BCAP + pos] = make_int2(ra[e] | (lrow << 18), rb[e]);
}

// ---------------- W transpose (fp32 [k][u] -> fp16 [u][k]) ----------------
__global__ __launch_bounds__(256) void transpose_w_k(
    const float* __restrict__ Wl, const float* __restrict__ Wf,
    const float* __restrict__ Wn, half_t* __restrict__ WlT,
    half_t* __restrict__ WfT, half_t* __restrict__ WnT) {
  __shared__ float t0[32][33], t1[32][33], t2[32][33];
  const int bx = (blockIdx.x & 3) * 32;   // u-tile
  const int by = (blockIdx.x >> 2) * 32;  // k-tile
  const int x = threadIdx.x & 31;
  const int y4 = (threadIdx.x >> 5) * 4;
#pragma unroll
  for (int i = 0; i < 4; ++i) {
    t0[y4 + i][x] = Wl[(by + y4 + i) * DIM + bx + x];
    t1[y4 + i][x] = Wf[(by + y4 + i) * DIM + bx + x];
    t2[y4 + i][x] = Wn[(by + y4 + i) * DIM + bx + x];
  }
  __syncthreads();
#pragma unroll
  for (int i = 0; i < 4; ++i) {
    WlT[(bx + y4 + i) * DIM + by + x] = (half_t)t0[x][y4 + i];
    WfT[(bx + y4 + i) * DIM + by + x] = (half_t)t1[x][y4 + i];
    WnT[(bx + y4 + i) * DIM + by + x] = (half_t)t2[x][y4 + i];
  }
}

// ---------------- neighbor GEMM (MFMA f16): XWnh = X@Wn + bn/2; emits Xh ----------------
__global__ __launch_bounds__(256) void neighbor_mfma_k(
    const float* __restrict__ X, const half_t* __restrict__ WnT,
    const float* __restrict__ bn, half_t* __restrict__ XWnh,
    half_t* __restrict__ Xh, int Nrows) {
  __shared__ half_t WT[DIM][136];  // W^T [u][k], +8 pad
  const int tid = threadIdx.x;
  for (int id = tid; id < 2048; id += 256) {
    const int u = id >> 4, c = (id & 15) * 8;
    *(half8*)(&WT[u][c]) = *(const half8*)(WnT + u * DIM + c);
  }
  __syncthreads();
  const int wave = tid >> 6, lane = tid & 63;
  const int ln = lane & 15, quad = lane >> 4;
  const long r0 = (long)blockIdx.x * 128 + wave * 32;
  f32x4 acc[2][8];
#pragma unroll
  for (int mt = 0; mt < 2; ++mt)
#pragma unroll
    for (int n = 0; n < 8; ++n) acc[mt][n] = (f32x4){0.f, 0.f, 0.f, 0.f};

  for (int kt = 0; kt < DIM; kt += 32) {
    half8 afr[2];
#pragma unroll
    for (int mt = 0; mt < 2; ++mt) {
      long row = r0 + mt * 16 + ln;
      if (row >= Nrows) row = Nrows - 1;
      const float* xp = X + row * DIM + kt + quad * 8;
      const float4 x0 = *(const float4*)xp;
      const float4 x1 = *(const float4*)(xp + 4);
      half8 a;
      a[0] = (half_t)x0.x; a[1] = (half_t)x0.y; a[2] = (half_t)x0.z; a[3] = (half_t)x0.w;
      a[4] = (half_t)x1.x; a[5] = (half_t)x1.y; a[6] = (half_t)x1.z; a[7] = (half_t)x1.w;
      afr[mt] = a;
      *(half8*)(Xh + row * DIM + kt + quad * 8) = a;
    }
#pragma unroll
    for (int n = 0; n < 8; ++n) {
      const half8 b = *(const half8*)(&WT[n * 16 + ln][kt + quad * 8]);
      acc[0][n] = __builtin_amdgcn_mfma_f32_16x16x32_f16(afr[0], b, acc[0][n], 0, 0, 0);
      acc[1][n] = __builtin_amdgcn_mfma_f32_16x16x32_f16(afr[1], b, acc[1][n], 0, 0, 0);
    }
  }
#pragma unroll
  for (int n = 0; n < 8; ++n) {
    const int col = n * 16 + ln;
    const float bv = 0.5f * bn[col];  // fold bn/2: (a+bn/2)+(b+bn/2)=a+b+bn
#pragma unroll
    for (int mt = 0; mt < 2; ++mt)
#pragma unroll
      for (int r = 0; r < 4; ++r) {
        const long row = r0 + mt * 16 + quad * 4 + r;
        if (row < Nrows) XWnh[row * DIM + col] = (half_t)(acc[mt][n][r] + bv);
      }
  }
}

// ---------------- bucket gather: conv tile in LDS, ds_add_f32 ----------------
__global__ __launch_bounds__(512, 2) void gather_lds_k(
    const half_t* __restrict__ XWnh, const int* __restrict__ cursor,
    const int2* __restrict__ binned, half_t* __restrict__ convh, int Nrows) {
  __shared__ float tile[BROWS * DIM];  // 64 KB -> 2 blocks/CU
  const int tid = threadIdx.x;
#pragma unroll
  for (int i = tid; i < BROWS * DIM / 4; i += 512)
    *(float4*)(tile + i * 4) = make_float4(0.f, 0.f, 0.f, 0.f);
  __syncthreads();
  const int bucket = blockIdx.x;
  int c = cursor[bucket];
  if (c > BCAP) c = BCAP;
  const int wave = tid >> 6, lane = tid & 63;
  const int2* eb = binned + (long)bucket * BCAP;
  for (int p = wave; p < c; p += 8) {
    const int2 ed = eb[p];
    const int a = ed.x & 0x3FFFF;
    const int lrow = ed.x >> 18;  // < 128, positive
    const int b = ed.y;
    // lane covers units {2*lane, 2*lane+1}; 64 lanes x 4B = 256B coalesced
    const half2v ha = *(const half2v*)(XWnh + (long)a * DIM + 2 * lane);
    const half2v hb = *(const half2v*)(XWnh + (long)b * DIM + 2 * lane);
    const float s0 = fmaxf((float)ha[0] + (float)hb[0], 0.f);
    const float s1 = fmaxf((float)ha[1] + (float)hb[1], 0.f);
    atomicAdd(&tile[lrow * DIM + 2 * lane], s0);      // ds_add_f32
    atomicAdd(&tile[lrow * DIM + 2 * lane + 1], s1);
  }
  __syncthreads();
  const long row0 = (long)bucket * BROWS;
#pragma unroll
  for (int i = tid; i < BROWS * DIM / 2; i += 512) {
    const int lr = i >> 6;
    const int u = (i & 63) * 2;
    const long row = row0 + lr;
    if (row < Nrows) {
      half2v o;
      o[0] = (half_t)tile[lr * DIM + u];
      o[1] = (half_t)tile[lr * DIM + u + 1];
      *(half2v*)(convh + row * DIM + u) = o;
    }
  }
}

// ---------------- final fused GEMM (MFMA f16) + epilogue ----------------
__global__ __launch_bounds__(256, 2) void final_mfma_k(
    const half_t* __restrict__ Xh, const half_t* __restrict__ WlT,
    const half_t* __restrict__ WfT, const float* __restrict__ bias,
    const half_t* __restrict__ convh, float* __restrict__ out, int Nrows) {
  __shared__ half_t WTl[DIM][136];
  __shared__ half_t WTf[DIM][136];
  const int tid = threadIdx.x;
  for (int id = tid; id < 2048; id += 256) {
    const int u = id >> 4, c = (id & 15) * 8;
    *(half8*)(&WTl[u][c]) = *(const half8*)(WlT + u * DIM + c);
    *(half8*)(&WTf[u][c]) = *(const half8*)(WfT + u * DIM + c);
  }
  __syncthreads();
  const int wave = tid >> 6, lane = tid & 63;
  const int ln = lane & 15, quad = lane >> 4;
  const long r0 = (long)blockIdx.x * 128 + wave * 32;
  f32x4 accl[2][8], accf[2][8];
#pragma unroll
  for (int mt = 0; mt < 2; ++mt)
#pragma unroll
    for (int n = 0; n < 8; ++n) {
      accl[mt][n] = (f32x4){0.f, 0.f, 0.f, 0.f};
      accf[mt][n] = (f32x4){0.f, 0.f, 0.f, 0.f};
    }

  for (int kt = 0; kt < DIM; kt += 32) {
    half8 afr[2];
#pragma unroll
    for (int mt = 0; mt < 2; ++mt) {
      long row = r0 + mt * 16 + ln;
      if (row >= Nrows) row = Nrows - 1;
      afr[mt] = *(const half8*)(Xh + row * DIM + kt + quad * 8);
    }
#pragma unroll
    for (int n = 0; n < 8; ++n) {
      const half8 bl = *(const half8*)(&WTl[n * 16 + ln][kt + quad * 8]);
      const half8 bf = *(const half8*)(&WTf[n * 16 + ln][kt + quad * 8]);
      accl[0][n] = __builtin_amdgcn_mfma_f32_16x16x32_f16(afr[0], bl, accl[0][n], 0, 0, 0);
      accl[1][n] = __builtin_amdgcn_mfma_f32_16x16x32_f16(afr[1], bl, accl[1][n], 0, 0, 0);
      accf[0][n] = __builtin_amdgcn_mfma_f32_16x16x32_f16(afr[0], bf, accf[0][n], 0, 0, 0);
      accf[1][n] = __builtin_amdgcn_mfma_f32_16x16x32_f16(afr[1], bf, accf[1][n], 0, 0, 0);
    }
  }
#pragma unroll
  for (int n = 0; n < 8; ++n) {
    const int col = n * 16 + ln;
    const float bv = bias[col];
#pragma unroll
    for (int mt = 0; mt < 2; ++mt)
#pragma unroll
      for (int r = 0; r < 4; ++r) {
        const long row = r0 + mt * 16 + quad * 4 + r;
        if (row < Nrows) {
          const float cv = (float)convh[row * DIM + col];
          out[row * DIM + col] = fmaxf(accl[mt][n][r] + accf[mt][n][r] * cv + bv, 0.f);
        }
      }
  }
}

extern "C" void kernel_launch(void* const* d_in, const int* in_sizes, int n_in,
                              void* d_out, int out_size, void* d_ws, size_t ws_size,
                              hipStream_t stream) {
  const float* X  = (const float*)d_in[0];
  const int* ra   = (const int*)d_in[1];
  const int* rb   = (const int*)d_in[2];
  const int* br   = (const int*)d_in[3];
  const float* Wl = (const float*)d_in[4];
  const float* Wf = (const float*)d_in[5];
  const float* Wn = (const float*)d_in[6];
  const float* b  = (const float*)d_in[7];
  const float* bn = (const float*)d_in[8];
  float* out = (float*)d_out;

  const int N = in_sizes[0] / DIM;  // 200000
  const int E = in_sizes[1];        // 2000000
  const int NBK = (N + BROWS - 1) / BROWS;  // 1563

  half_t* XWnh = (half_t*)d_ws;                        // N*DIM f16
  half_t* Xh = XWnh + (size_t)N * DIM;                 // N*DIM f16
  half_t* convh = Xh + (size_t)N * DIM;                // N*DIM f16
  half_t* WlT = convh + (size_t)N * DIM;               // 128*128 f16
  half_t* WfT = WlT + DIM * DIM;
  half_t* WnT = WfT + DIM * DIM;
  int* cursor = (int*)(WnT + DIM * DIM);               // NBK (pad to even)
  int2* binned = (int2*)(cursor + ((NBK + 1) & ~1));   // NBK*BCAP int2

  hipMemsetAsync(cursor, 0, (size_t)NBK * sizeof(int), stream);
  transpose_w_k<<<16, 256, 0, stream>>>(Wl, Wf, Wn, WlT, WfT, WnT);
  fill_bucket_k<<<(E + 255) / 256, 256, 0, stream>>>(ra, rb, br, cursor, binned, E);

  const int rowBlocks128 = (N + 127) / 128;
  neighbor_mfma_k<<<rowBlocks128, 256, 0, stream>>>(X, WnT, bn, XWnh, Xh, N);
  gather_lds_k<<<NBK, 512, 0, stream>>>(XWnh, cursor, binned, convh, N);
  final_mfma_k<<<rowBlocks128, 256, 0, stream>>>(Xh, WlT, WfT, b, convh, out, N);
}

// Round 6
// 571.636 us; speedup vs baseline: 3.6012x; 3.6012x over previous
//
#include <hip/hip_runtime.h>

// WL2 graph-conv layer, MI355X — round 6: round-4 structure, CSR build collapsed
// to one fixed-slot kernel (cap 40), fp16 conv, no Xh.
// transpose_w -> memset(cnt) -> fill_slots -> neighbor_mfma -> gather -> final_mfma
// ws: [XWnh 51.2MB][convh 51.2MB][W^T 96KB][cnt 0.8MB][slots 64MB] ~167MB

constexpr int DIM = 128;
constexpr int CAP = 40;  // Poisson lambda=10; P(row deg > 40) ~ 5.6e-13, x200k ~ 1e-7

typedef _Float16 half_t;
typedef __attribute__((ext_vector_type(8))) _Float16 half8;
typedef __attribute__((ext_vector_type(4))) float f32x4;

// ---------------- CSR build: fixed-capacity slots ----------------
__global__ __launch_bounds__(256) void fill_slots_k(
    const int* __restrict__ ra, const int* __restrict__ rb,
    const int* __restrict__ br, int* __restrict__ cnt,
    int2* __restrict__ slots, int E) {
  const int e = blockIdx.x * 256 + threadIdx.x;
  if (e >= E) return;
  const int row = br[e];
  const int pos = atomicAdd(&cnt[row], 1);
  if (pos < CAP) slots[(long)row * CAP + pos] = make_int2(ra[e], rb[e]);
}

// ---------------- W transpose (fp32 [k][u] -> fp16 [u][k]) ----------------
__global__ __launch_bounds__(256) void transpose_w_k(
    const float* __restrict__ Wl, const float* __restrict__ Wf,
    const float* __restrict__ Wn, half_t* __restrict__ WlT,
    half_t* __restrict__ WfT, half_t* __restrict__ WnT) {
  __shared__ float t0[32][33], t1[32][33], t2[32][33];
  const int bx = (blockIdx.x & 3) * 32;   // u-tile
  const int by = (blockIdx.x >> 2) * 32;  // k-tile
  const int x = threadIdx.x & 31;
  const int y4 = (threadIdx.x >> 5) * 4;
#pragma unroll
  for (int i = 0; i < 4; ++i) {
    t0[y4 + i][x] = Wl[(by + y4 + i) * DIM + bx + x];
    t1[y4 + i][x] = Wf[(by + y4 + i) * DIM + bx + x];
    t2[y4 + i][x] = Wn[(by + y4 + i) * DIM + bx + x];
  }
  __syncthreads();
#pragma unroll
  for (int i = 0; i < 4; ++i) {
    WlT[(bx + y4 + i) * DIM + by + x] = (half_t)t0[x][y4 + i];
    WfT[(bx + y4 + i) * DIM + by + x] = (half_t)t1[x][y4 + i];
    WnT[(bx + y4 + i) * DIM + by + x] = (half_t)t2[x][y4 + i];
  }
}

// ---------------- neighbor GEMM (MFMA f16): XWnh = f16(X@Wn + bn/2) ----------------
__global__ __launch_bounds__(256) void neighbor_mfma_k(
    const float* __restrict__ X, const half_t* __restrict__ WnT,
    const float* __restrict__ bn, half_t* __restrict__ XWnh, int Nrows) {
  __shared__ half_t WT[DIM][136];  // W^T [u][k], +8 pad
  const int tid = threadIdx.x;
  for (int id = tid; id < 2048; id += 256) {
    const int u = id >> 4, c = (id & 15) * 8;
    *(half8*)(&WT[u][c]) = *(const half8*)(WnT + u * DIM + c);
  }
  __syncthreads();
  const int wave = tid >> 6, lane = tid & 63;
  const int ln = lane & 15, quad = lane >> 4;
  const long r0 = (long)blockIdx.x * 128 + wave * 32;
  f32x4 acc[2][8];
#pragma unroll
  for (int mt = 0; mt < 2; ++mt)
#pragma unroll
    for (int n = 0; n < 8; ++n) acc[mt][n] = (f32x4){0.f, 0.f, 0.f, 0.f};

  for (int kt = 0; kt < DIM; kt += 32) {
    half8 afr[2];
#pragma unroll
    for (int mt = 0; mt < 2; ++mt) {
      long row = r0 + mt * 16 + ln;
      if (row >= Nrows) row = Nrows - 1;
      const float* xp = X + row * DIM + kt + quad * 8;
      const float4 x0 = *(const float4*)xp;
      const float4 x1 = *(const float4*)(xp + 4);
      half8 a;
      a[0] = (half_t)x0.x; a[1] = (half_t)x0.y; a[2] = (half_t)x0.z; a[3] = (half_t)x0.w;
      a[4] = (half_t)x1.x; a[5] = (half_t)x1.y; a[6] = (half_t)x1.z; a[7] = (half_t)x1.w;
      afr[mt] = a;
    }
#pragma unroll
    for (int n = 0; n < 8; ++n) {
      const half8 b = *(const half8*)(&WT[n * 16 + ln][kt + quad * 8]);
      acc[0][n] = __builtin_amdgcn_mfma_f32_16x16x32_f16(afr[0], b, acc[0][n], 0, 0, 0);
      acc[1][n] = __builtin_amdgcn_mfma_f32_16x16x32_f16(afr[1], b, acc[1][n], 0, 0, 0);
    }
  }
#pragma unroll
  for (int n = 0; n < 8; ++n) {
    const int col = n * 16 + ln;
    const float bv = 0.5f * bn[col];  // fold bn/2: (a+bn/2)+(b+bn/2)=a+b+bn
#pragma unroll
    for (int mt = 0; mt < 2; ++mt)
#pragma unroll
      for (int r = 0; r < 4; ++r) {
        const long row = r0 + mt * 16 + quad * 4 + r;
        if (row < Nrows) XWnh[row * DIM + col] = (half_t)(acc[mt][n][r] + bv);
      }
  }
}

// ---------------- CSR gather: convh[row] = f16(sum relu(XWn[a]+XWn[b])) ----------------
__global__ __launch_bounds__(256) void gather_k(
    const half_t* __restrict__ XWnh, const int* __restrict__ cnt,
    const int2* __restrict__ slots, half_t* __restrict__ convh, int Nrows) {
  const int wave = threadIdx.x >> 6;
  const long row = (long)blockIdx.x * 4 + wave;
  if (row >= Nrows) return;
  const int lane = threadIdx.x & 63;
  const int sub = lane >> 4;  // quarter-wave: 4 edges in flight
  const int sl = lane & 15;   // 16 lanes x 8 units
  int c = cnt[row];
  if (c > CAP) c = CAP;
  const int2* sp = slots + (long)row * CAP;
  float acc[8] = {0.f, 0.f, 0.f, 0.f, 0.f, 0.f, 0.f, 0.f};
  for (int p = sub; p < c; p += 4) {
    const int2 ab = sp[p];
    const half8 ha = *(const half8*)(XWnh + (long)ab.x * DIM + sl * 8);
    const half8 hb = *(const half8*)(XWnh + (long)ab.y * DIM + sl * 8);
#pragma unroll
    for (int j = 0; j < 8; ++j)
      acc[j] += fmaxf((float)ha[j] + (float)hb[j], 0.f);
  }
#pragma unroll
  for (int j = 0; j < 8; ++j) {
    acc[j] += __shfl_xor(acc[j], 16);
    acc[j] += __shfl_xor(acc[j], 32);
  }
  if (sub == 0) {
    half8 o;
#pragma unroll
    for (int j = 0; j < 8; ++j) o[j] = (half_t)acc[j];
    *(half8*)(convh + row * DIM + sl * 8) = o;
  }
}

// ---------------- final fused GEMM (MFMA f16) + epilogue ----------------
__global__ __launch_bounds__(256, 2) void final_mfma_k(
    const float* __restrict__ X, const half_t* __restrict__ WlT,
    const half_t* __restrict__ WfT, const float* __restrict__ bias,
    const half_t* __restrict__ convh, float* __restrict__ out, int Nrows) {
  __shared__ half_t WTl[DIM][136];
  __shared__ half_t WTf[DIM][136];
  const int tid = threadIdx.x;
  for (int id = tid; id < 2048; id += 256) {
    const int u = id >> 4, c = (id & 15) * 8;
    *(half8*)(&WTl[u][c]) = *(const half8*)(WlT + u * DIM + c);
    *(half8*)(&WTf[u][c]) = *(const half8*)(WfT + u * DIM + c);
  }
  __syncthreads();
  const int wave = tid >> 6, lane = tid & 63;
  const int ln = lane & 15, quad = lane >> 4;
  const long r0 = (long)blockIdx.x * 128 + wave * 32;
  f32x4 accl[2][8], accf[2][8];
#pragma unroll
  for (int mt = 0; mt < 2; ++mt)
#pragma unroll
    for (int n = 0; n < 8; ++n) {
      accl[mt][n] = (f32x4){0.f, 0.f, 0.f, 0.f};
      accf[mt][n] = (f32x4){0.f, 0.f, 0.f, 0.f};
    }

  for (int kt = 0; kt < DIM; kt += 32) {
    half8 afr[2];
#pragma unroll
    for (int mt = 0; mt < 2; ++mt) {
      long row = r0 + mt * 16 + ln;
      if (row >= Nrows) row = Nrows - 1;
      const float* xp = X + row * DIM + kt + quad * 8;
      const float4 x0 = *(const float4*)xp;
      const float4 x1 = *(const float4*)(xp + 4);
      half8 a;
      a[0] = (half_t)x0.x; a[1] = (half_t)x0.y; a[2] = (half_t)x0.z; a[3] = (half_t)x0.w;
      a[4] = (half_t)x1.x; a[5] = (half_t)x1.y; a[6] = (half_t)x1.z; a[7] = (half_t)x1.w;
      afr[mt] = a;
    }
#pragma unroll
    for (int n = 0; n < 8; ++n) {
      const half8 bl = *(const half8*)(&WTl[n * 16 + ln][kt + quad * 8]);
      const half8 bf = *(const half8*)(&WTf[n * 16 + ln][kt + quad * 8]);
      accl[0][n] = __builtin_amdgcn_mfma_f32_16x16x32_f16(afr[0], bl, accl[0][n], 0, 0, 0);
      accl[1][n] = __builtin_amdgcn_mfma_f32_16x16x32_f16(afr[1], bl, accl[1][n], 0, 0, 0);
      accf[0][n] = __builtin_amdgcn_mfma_f32_16x16x32_f16(afr[0], bf, accf[0][n], 0, 0, 0);
      accf[1][n] = __builtin_amdgcn_mfma_f32_16x16x32_f16(afr[1], bf, accf[1][n], 0, 0, 0);
    }
  }
#pragma unroll
  for (int n = 0; n < 8; ++n) {
    const int col = n * 16 + ln;
    const float bv = bias[col];
#pragma unroll
    for (int mt = 0; mt < 2; ++mt)
#pragma unroll
      for (int r = 0; r < 4; ++r) {
        const long row = r0 + mt * 16 + quad * 4 + r;
        if (row < Nrows) {
          const float cv = (float)convh[row * DIM + col];
          out[row * DIM + col] = fmaxf(accl[mt][n][r] + accf[mt][n][r] * cv + bv, 0.f);
        }
      }
  }
}

extern "C" void kernel_launch(void* const* d_in, const int* in_sizes, int n_in,
                              void* d_out, int out_size, void* d_ws, size_t ws_size,
                              hipStream_t stream) {
  const float* X  = (const float*)d_in[0];
  const int* ra   = (const int*)d_in[1];
  const int* rb   = (const int*)d_in[2];
  const int* br   = (const int*)d_in[3];
  const float* Wl = (const float*)d_in[4];
  const float* Wf = (const float*)d_in[5];
  const float* Wn = (const float*)d_in[6];
  const float* b  = (const float*)d_in[7];
  const float* bn = (const float*)d_in[8];
  float* out = (float*)d_out;

  const int N = in_sizes[0] / DIM;  // 200000
  const int E = in_sizes[1];        // 2000000

  half_t* XWnh = (half_t*)d_ws;                      // N*DIM f16
  half_t* convh = XWnh + (size_t)N * DIM;            // N*DIM f16
  half_t* WlT = convh + (size_t)N * DIM;             // 128*128 f16 x3
  half_t* WfT = WlT + DIM * DIM;
  half_t* WnT = WfT + DIM * DIM;
  int* cnt = (int*)(WnT + DIM * DIM);                // N i32
  int2* slots = (int2*)(cnt + ((N + 1) & ~1));       // N*CAP int2

  hipMemsetAsync(cnt, 0, (size_t)N * sizeof(int), stream);
  transpose_w_k<<<16, 256, 0, stream>>>(Wl, Wf, Wn, WlT, WfT, WnT);
  fill_slots_k<<<(E + 255) / 256, 256, 0, stream>>>(ra, rb, br, cnt, slots, E);

  const int rowBlocks128 = (N + 127) / 128;
  neighbor_mfma_k<<<rowBlocks128, 256, 0, stream>>>(X, WnT, bn, XWnh, N);
  gather_k<<<(N + 3) / 4, 256, 0, stream>>>(XWnh, cnt, slots, convh, N);
  final_mfma_k<<<rowBlocks128, 256, 0, stream>>>(X, WlT, WfT, b, convh, out, N);
}